// Round 13
// baseline (319.659 us; speedup 1.0000x reference)
//
#include <hip/hip_runtime.h>

// RGCN layer: out[i] = relu( x[i]@root + bias + sum_r mean_{j in N_r(i)} x[j]@W[r] )
//
// Two-phase (linearity) + SOURCE COMPACTION:
//   H rows [0,N) = bf16(x@root + bias); then per rel r one row per USED src:
//   bf16(x[src]@W[r]).  out[i] = relu( H[i] + sum_e (1/c) * H[hidx_e] )
// pk2 packs hidx(20b) | c(8b). gather: wave-uniform dst scalarized
// (readfirstlane -> SMEM loads for pk2/bounds), rcpf for 1/c.
// gemm_h v4: grid 128x9 (~4.5 blocks/CU; R11 showed 13.6% occupancy at 56x9),
// nontemporal H stores via ext_vector u32x4 (HIP uint4 is a class type and
// rejected by the builtin), 2-stage pipeline (csrc dist 2, XB A-frag dist 1).

#define D 128

typedef __attribute__((ext_vector_type(8))) short bf16x8;
typedef __attribute__((ext_vector_type(4))) float f32x4;
typedef __attribute__((ext_vector_type(4))) unsigned u32x4;

__device__ inline unsigned short f32_to_bf16(float f) {
    unsigned u = __float_as_uint(f);
    return (unsigned short)((u + 0x7FFF + ((u >> 16) & 1)) >> 16);   // RNE
}
__device__ inline float bf_lo(unsigned u) { return __uint_as_float(u << 16); }
__device__ inline float bf_hi(unsigned u) { return __uint_as_float(u & 0xFFFF0000u); }

// LDS-only barrier: order ds ops without draining vmcnt.
__device__ inline void lds_barrier() {
    asm volatile("s_waitcnt lgkmcnt(0)\n\ts_barrier" ::: "memory");
}

// ---------------------------------------------------------------------------
// prep: XB = bf16(x); WT[seg][n][k] = bf16(Wseg[k][n]); zero c, G, cnt2
// ---------------------------------------------------------------------------
__global__ __launch_bounds__(256) void prep_all(
    const float* __restrict__ x, const float* __restrict__ W,
    const float* __restrict__ root,
    unsigned* __restrict__ XB, unsigned short* __restrict__ WT,
    int* __restrict__ c, int* __restrict__ G, int* __restrict__ cnt2,
    int nquads, int wt_total, int n_nodes, int n_rel)
{
    int i = blockIdx.x * 256 + threadIdx.x;
    if (i < nquads) {
        float4 v = ((const float4*)x)[i];
        unsigned w0 = (unsigned)f32_to_bf16(v.x) | ((unsigned)f32_to_bf16(v.y) << 16);
        unsigned w1 = (unsigned)f32_to_bf16(v.z) | ((unsigned)f32_to_bf16(v.w) << 16);
        ((uint2*)XB)[i] = make_uint2(w0, w1);
    }
    if (i < wt_total) {
        int seg = i >> 14, rem = i & 16383;
        int n = rem >> 7, k = rem & 127;
        float v = (seg == 0) ? root[k * D + n]
                             : W[(size_t)(seg - 1) * D * D + k * D + n];
        WT[i] = f32_to_bf16(v);
    }
    if (i < n_nodes * n_rel) c[i] = 0;
    if (i < n_nodes * (n_rel + 1)) G[i] = 0;
    if (i < n_nodes) cnt2[i] = 0;
}

// ---------------------------------------------------------------------------
__global__ __launch_bounds__(256) void edge_hist(
    const int* __restrict__ edge_index, const int* __restrict__ edge_type,
    int* __restrict__ c, int* __restrict__ G, int n_edges, int n_nodes, int n_rel)
{
    int e = blockIdx.x * 256 + threadIdx.x;
    if (e >= n_edges) return;
    int src = edge_index[e];
    int dst = edge_index[n_edges + e];
    int r   = edge_type[e];
    atomicAdd(&c[dst * n_rel + r], 1);
    atomicAdd(&G[dst], 1);                       // degree (CSR)
    G[n_nodes + r * n_nodes + src] = 1;          // used flag (benign race)
}

// ---------------------------------------------------------------------------
// Two-level exclusive scan over G[nG]. Consumers: S(i) = tmp[i] + offs[i>>10].
// ---------------------------------------------------------------------------
__global__ __launch_bounds__(1024) void scanA(
    const int* __restrict__ G, int* __restrict__ tmp, int* __restrict__ parts, int n)
{
    __shared__ int buf[2][1024];
    const int tid = threadIdx.x;
    int i = blockIdx.x * 1024 + tid;
    int v = (i < n) ? G[i] : 0;
    buf[0][tid] = v;
    __syncthreads();
    int pi = 0;
    for (int off = 1; off < 1024; off <<= 1) {
        int t = buf[pi][tid] + ((tid >= off) ? buf[pi][tid - off] : 0);
        buf[1 - pi][tid] = t;
        pi = 1 - pi;
        __syncthreads();
    }
    if (i < n) tmp[i] = buf[pi][tid] - v;
    if (tid == 1023) parts[blockIdx.x] = buf[pi][1023];
}

__global__ __launch_bounds__(1024) void scanB(
    const int* __restrict__ parts, int* __restrict__ offs,
    int* __restrict__ tot, int np)
{
    __shared__ int buf[2][1024];
    const int t = threadIdx.x;
    int v = (t < np) ? parts[t] : 0;
    buf[0][t] = v;
    __syncthreads();
    int pi = 0;
    for (int off = 1; off < 1024; off <<= 1) {
        int s = buf[pi][t] + ((t >= off) ? buf[pi][t - off] : 0);
        buf[1 - pi][t] = s;
        pi = 1 - pi;
        __syncthreads();
    }
    if (t < np) offs[t] = buf[pi][t] - v;
    if (t == 0) tot[0] = buf[pi][1023];          // n_edges + n_compact
}

// ---------------------------------------------------------------------------
// edge_bin: CSR-place each edge; pack hidx|c; build csrc (redundant stores ok)
// ---------------------------------------------------------------------------
__global__ __launch_bounds__(256) void edge_bin(
    const int* __restrict__ edge_index, const int* __restrict__ edge_type,
    const int* __restrict__ tmp, const int* __restrict__ offs,
    const int* __restrict__ c, int* __restrict__ cnt2,
    unsigned* __restrict__ pk2, int* __restrict__ csrc,
    int n_edges, int n_nodes, int n_rel)
{
    int e = blockIdx.x * 256 + threadIdx.x;
    if (e >= n_edges) return;
    int src = edge_index[e];
    int dst = edge_index[n_edges + e];
    int r   = edge_type[e];
    int pos = tmp[dst] + offs[dst >> 10] + atomicAdd(&cnt2[dst], 1);
    int gi  = n_nodes + r * n_nodes + src;
    int cidx = tmp[gi] + offs[gi >> 10] - n_edges;    // compact rel-row index
    int hidx = n_nodes + cidx;                        // < 2^20
    unsigned cc = (unsigned)c[dst * n_rel + r];
    if (cc > 255u) cc = 255u;
    pk2[pos] = (unsigned)hidx | (cc << 20);
    csrc[cidx] = src;                                 // same-value race: benign
}

// ---------------------------------------------------------------------------
// Phase 1 v4: H rows, 2-stage pipelined. grid (128, n_rel+1).
// seg 0: all nodes (x@root + bias); seg>0: used srcs of rel seg-1 via csrc.
// B-frags register-resident; csrc prefetch distance 2, XB frag distance 1.
// ---------------------------------------------------------------------------
__global__ __launch_bounds__(256, 2) void gemm_h(
    const unsigned* __restrict__ XB, const unsigned short* __restrict__ WT,
    const float* __restrict__ bias, const int* __restrict__ csrc,
    const int* __restrict__ tmp, const int* __restrict__ offs,
    const int* __restrict__ tot, unsigned short* __restrict__ H,
    int n_nodes, int n_edges, int n_rel)
{
    __shared__ unsigned short Ht[2][64][D];

    const int seg  = blockIdx.y;
    const int tid  = threadIdx.x;
    const int wave = tid >> 6;
    const int lane = tid & 63;
    const int l16  = lane & 15;
    const int quad = lane >> 4;

    int base_row, count, segS0 = 0;
    if (seg == 0) { base_row = 0; count = n_nodes; }
    else {
        int r = seg - 1;
        int gi0 = n_nodes + r * n_nodes;
        segS0 = tmp[gi0] + offs[gi0 >> 10] - n_edges;
        int segS1;
        if (r == n_rel - 1) segS1 = tot[0] - n_edges;
        else { int gi1 = gi0 + n_nodes; segS1 = tmp[gi1] + offs[gi1 >> 10] - n_edges; }
        base_row = n_nodes + segS0;
        count = segS1 - segS0;
    }

    // B-frags: register-resident for the whole block (32 x 16B = 128 VGPR)
    bf16x8 bfr[8][4];
    {
        const unsigned short* Wseg = WT + (size_t)seg * D * D;
#pragma unroll
        for (int nt = 0; nt < 8; ++nt) {
            const unsigned short* bp = Wseg + (size_t)(nt * 16 + l16) * D + quad * 8;
#pragma unroll
            for (int kc = 0; kc < 4; ++kc)
                bfr[nt][kc] = *(const bf16x8*)(bp + kc * 32);
        }
    }
    float bv[8];
#pragma unroll
    for (int nt = 0; nt < 8; ++nt)
        bv[nt] = (seg == 0) ? bias[nt * 16 + l16] : 0.f;

    const int gx = gridDim.x;
    const int row_off = wave * 16 + l16;
    const int cq8 = quad * 8;

    int tile = blockIdx.x;
    if (tile * 64 >= count) return;

    auto load_node = [&](int t) -> int {
        int lr = t * 64 + row_off;
        if (lr >= count) return 0;
        return (seg == 0) ? lr : csrc[segS0 + lr];
    };
    auto load_af = [&](int t, int node, bf16x8* fr) {
        int lr = t * 64 + row_off;
        bool v = (lr < count);
        const unsigned short* xr = (const unsigned short*)XB + (size_t)node * D + cq8;
#pragma unroll
        for (int kc = 0; kc < 4; ++kc)
            fr[kc] = v ? *(const bf16x8*)(xr + kc * 32)
                       : (bf16x8){0, 0, 0, 0, 0, 0, 0, 0};
    };

    int node_cur = load_node(tile);
    bf16x8 af[4];
    load_af(tile, node_cur, af);
    int tile_nxt = tile + gx;
    int node_nxt = (tile_nxt * 64 < count) ? load_node(tile_nxt) : 0;

    int it = 0;
    for (;;) {
        const bool have_nxt = (tile_nxt * 64 < count);

        // (1) issue next tile's A-frag loads (node_nxt resolved last iter)
        bf16x8 afn[4];
        if (have_nxt) load_af(tile_nxt, node_nxt, afn);

        // (2) MFMA current tile (covers afn latency)
        f32x4 acc[8];
#pragma unroll
        for (int nt = 0; nt < 8; ++nt) {
            acc[nt] = (f32x4){0.f, 0.f, 0.f, 0.f};
#pragma unroll
            for (int kc = 0; kc < 4; ++kc)
                acc[nt] = __builtin_amdgcn_mfma_f32_16x16x32_bf16(
                    af[kc], bfr[nt][kc], acc[nt], 0, 0, 0);
        }

        // (3) issue csrc prefetch for tile+2 (covered by repack/store + next MFMA)
        int tile_n2 = tile_nxt + gx;
        int node_n2 = 0;
        if (have_nxt && tile_n2 * 64 < count) node_n2 = load_node(tile_n2);

        // (4) repack C/D -> row-major bf16 tile (double-buffered) + store
        unsigned short (*Hb)[D] = Ht[it & 1];
#pragma unroll
        for (int nt = 0; nt < 8; ++nt) {
            int col = nt * 16 + l16;
#pragma unroll
            for (int reg = 0; reg < 4; ++reg)
                Hb[wave * 16 + quad * 4 + reg][col] = f32_to_bf16(acc[nt][reg] + bv[nt]);
        }
        lds_barrier();   // ds-order only; global stores/loads stay in flight

        int rows = count - tile * 64; if (rows > 64) rows = 64;
        int nu4 = rows * (D / 8);
        const u32x4* srcp = (const u32x4*)&Hb[0][0];
        u32x4* dstp = (u32x4*)(H + ((size_t)(base_row + tile * 64)) * D);
        for (int i = tid; i < nu4; i += 256)
            __builtin_nontemporal_store(srcp[i], &dstp[i]);  // write-once: skip L2

        if (!have_nxt) break;
        tile = tile_nxt; tile_nxt = tile_n2;
        node_cur = node_nxt; node_nxt = node_n2;
#pragma unroll
        for (int kc = 0; kc < 4; ++kc) af[kc] = afn[kc];
        ++it;
    }
}

// ---------------------------------------------------------------------------
// Phase 2: one wave per dst node; dst made explicitly wave-uniform so
// pk2/bounds go through scalar loads; per-lane work = H load + 2 unpack +
// 2 FMA per edge. 1/c via v_rcp (c is a small integer: error ~1 ulp).
// ---------------------------------------------------------------------------
__global__ __launch_bounds__(256) void gather_out(
    const unsigned short* __restrict__ H, const unsigned* __restrict__ pk2,
    const int* __restrict__ tmp, const int* __restrict__ offs,
    float* __restrict__ out, int n_nodes)
{
    int dst = (blockIdx.x * 256 + threadIdx.x) >> 6;
    const int lane = threadIdx.x & 63;
    if (dst >= n_nodes) return;
    dst = __builtin_amdgcn_readfirstlane(dst);   // wave-uniform by construction

    const unsigned* HH = (const unsigned*)H;
    unsigned u0 = HH[(size_t)dst * 64 + lane];   // root+bias row
    float a0 = bf_lo(u0), a1 = bf_hi(u0);

    const int e0 = tmp[dst] + offs[dst >> 10];
    const int e1 = tmp[dst + 1] + offs[(dst + 1) >> 10];

    for (int base = e0; base < e1; base += 8) {
        float al[8];
        const unsigned* hp[8];
#pragma unroll
        for (int j = 0; j < 8; ++j) {
            int e = base + j;
            bool ok = (e < e1);
            unsigned p = ok ? pk2[e] : 0u;       // uniform address -> s_load
            al[j] = ok ? __builtin_amdgcn_rcpf((float)(p >> 20)) : 0.f;
            hp[j] = HH + (size_t)(p & 0xFFFFFu) * 64;
        }
        unsigned hv[8];
#pragma unroll
        for (int j = 0; j < 8; ++j) hv[j] = hp[j][lane];
#pragma unroll
        for (int j = 0; j < 8; ++j) {
            a0 += al[j] * bf_lo(hv[j]);
            a1 += al[j] * bf_hi(hv[j]);
        }
    }

    a0 = fmaxf(a0, 0.f); a1 = fmaxf(a1, 0.f);
    *(float2*)(out + (size_t)dst * D + 2 * lane) = make_float2(a0, a1);
}

extern "C" void kernel_launch(void* const* d_in, const int* in_sizes, int n_in,
                              void* d_out, int out_size, void* d_ws, size_t ws_size,
                              hipStream_t stream) {
    const float* x          = (const float*)d_in[0];
    const int*   edge_index = (const int*)d_in[1];
    const int*   edge_type  = (const int*)d_in[2];
    const float* W          = (const float*)d_in[3];
    const float* root       = (const float*)d_in[4];
    const float* bias       = (const float*)d_in[5];
    float* out = (float*)d_out;

    const int n_nodes = in_sizes[0] / D;          // 100000
    const int n_edges = in_sizes[2];              // 600000
    const int n_rel   = in_sizes[3] / (D * D);    // 8
    const int nsegs   = n_rel + 1;
    const int nG      = n_nodes * nsegs;          // 900000

    // ws layout (worst-case compact rows = n_nodes + n_edges)
    char* p = (char*)d_ws;
    auto alloc = [&](size_t bytes) {
        char* q = p; p += (bytes + 255) & ~(size_t)255; return q;
    };
    int* c      = (int*)alloc((size_t)n_nodes * n_rel * 4);
    int* G      = (int*)alloc((size_t)(nG + 1) * 4);
    int* tmp    = (int*)alloc((size_t)(nG + 1) * 4);
    int* parts  = (int*)alloc(4096);
    int* offs   = (int*)alloc(4096);
    int* tot    = (int*)alloc(256);
    int* cnt2   = (int*)alloc((size_t)n_nodes * 4);
    unsigned* pk2 = (unsigned*)alloc((size_t)n_edges * 4);
    unsigned* XB  = (unsigned*)alloc((size_t)n_nodes * (D / 2) * 4);
    unsigned short* WT = (unsigned short*)alloc((size_t)nsegs * D * D * 2);
    int* csrc   = (int*)alloc((size_t)n_edges * 4);
    unsigned short* H = (unsigned short*)p;       // worst (n_nodes+n_edges) rows

    const int nquads   = n_nodes * (D / 4);
    const int wt_total = nsegs * D * D;
    int prep_n = nquads;
    if (wt_total > prep_n) prep_n = wt_total;
    if (nG > prep_n) prep_n = nG;

    const int egrid = (n_edges + 255) / 256;
    const int nA = (nG + 1023) / 1024;            // 879 <= 1024

    prep_all<<<(prep_n + 255) / 256, 256, 0, stream>>>(
        x, W, root, XB, WT, c, G, cnt2, nquads, wt_total, n_nodes, n_rel);
    edge_hist<<<egrid, 256, 0, stream>>>(
        edge_index, edge_type, c, G, n_edges, n_nodes, n_rel);
    scanA<<<nA, 1024, 0, stream>>>(G, tmp, parts, nG);
    scanB<<<1, 1024, 0, stream>>>(parts, offs, tot, nA);
    edge_bin<<<egrid, 256, 0, stream>>>(
        edge_index, edge_type, tmp, offs, c, cnt2, pk2, csrc,
        n_edges, n_nodes, n_rel);
    gemm_h<<<dim3(128, nsegs), 256, 0, stream>>>(
        XB, WT, bias, csrc, tmp, offs, tot, H, n_nodes, n_edges, n_rel);
    gather_out<<<(n_nodes + 3) / 4, 256, 0, stream>>>(
        H, pk2, tmp, offs, out, n_nodes);
}

// Round 14
// 309.160 us; speedup vs baseline: 1.0340x; 1.0340x over previous
//
#include <hip/hip_runtime.h>

// RGCN layer: out[i] = relu( x[i]@root + bias + sum_r mean_{j in N_r(i)} x[j]@W[r] )
//
// Two-phase (linearity) + SOURCE COMPACTION:
//   H rows [0,N) = bf16(x@root + bias); then per rel r one row per USED src:
//   bf16(x[src]@W[r]).  out[i] = relu( H[i] + sum_e (1/c) * H[hidx_e] )
// pk2 packs hidx(20b) | c(8b). gather: wave-uniform dst scalarized.
// gemm_h v5: FLAT-BALANCED tile space over all 9 segments (R13 showed the
// 9-way y-grid leaves half the machine idle in a seg-0 tail: 13 vs 7
// tiles/block -> 16% occupancy). In-kernel seg table (LDS), grid 1024 equal
// chunks, B-frags reloaded only at segment boundaries (<=2 per block).
// Plain H stores (R13: nontemporal bypassed L3 and regressed gather).

#define D 128

typedef __attribute__((ext_vector_type(8))) short bf16x8;
typedef __attribute__((ext_vector_type(4))) float f32x4;
typedef __attribute__((ext_vector_type(4))) unsigned u32x4;

__device__ inline unsigned short f32_to_bf16(float f) {
    unsigned u = __float_as_uint(f);
    return (unsigned short)((u + 0x7FFF + ((u >> 16) & 1)) >> 16);   // RNE
}
__device__ inline float bf_lo(unsigned u) { return __uint_as_float(u << 16); }
__device__ inline float bf_hi(unsigned u) { return __uint_as_float(u & 0xFFFF0000u); }

// LDS-only barrier: order ds ops without draining vmcnt.
__device__ inline void lds_barrier() {
    asm volatile("s_waitcnt lgkmcnt(0)\n\ts_barrier" ::: "memory");
}

// ---------------------------------------------------------------------------
// prep: XB = bf16(x); WT[seg][n][k] = bf16(Wseg[k][n]); zero c, G, cnt2
// ---------------------------------------------------------------------------
__global__ __launch_bounds__(256) void prep_all(
    const float* __restrict__ x, const float* __restrict__ W,
    const float* __restrict__ root,
    unsigned* __restrict__ XB, unsigned short* __restrict__ WT,
    int* __restrict__ c, int* __restrict__ G, int* __restrict__ cnt2,
    int nquads, int wt_total, int n_nodes, int n_rel)
{
    int i = blockIdx.x * 256 + threadIdx.x;
    if (i < nquads) {
        float4 v = ((const float4*)x)[i];
        unsigned w0 = (unsigned)f32_to_bf16(v.x) | ((unsigned)f32_to_bf16(v.y) << 16);
        unsigned w1 = (unsigned)f32_to_bf16(v.z) | ((unsigned)f32_to_bf16(v.w) << 16);
        ((uint2*)XB)[i] = make_uint2(w0, w1);
    }
    if (i < wt_total) {
        int seg = i >> 14, rem = i & 16383;
        int n = rem >> 7, k = rem & 127;
        float v = (seg == 0) ? root[k * D + n]
                             : W[(size_t)(seg - 1) * D * D + k * D + n];
        WT[i] = f32_to_bf16(v);
    }
    if (i < n_nodes * n_rel) c[i] = 0;
    if (i < n_nodes * (n_rel + 1)) G[i] = 0;
    if (i < n_nodes) cnt2[i] = 0;
}

// ---------------------------------------------------------------------------
__global__ __launch_bounds__(256) void edge_hist(
    const int* __restrict__ edge_index, const int* __restrict__ edge_type,
    int* __restrict__ c, int* __restrict__ G, int n_edges, int n_nodes, int n_rel)
{
    int e = blockIdx.x * 256 + threadIdx.x;
    if (e >= n_edges) return;
    int src = edge_index[e];
    int dst = edge_index[n_edges + e];
    int r   = edge_type[e];
    atomicAdd(&c[dst * n_rel + r], 1);
    atomicAdd(&G[dst], 1);                       // degree (CSR)
    G[n_nodes + r * n_nodes + src] = 1;          // used flag (benign race)
}

// ---------------------------------------------------------------------------
// Two-level exclusive scan over G[nG]. Consumers: S(i) = tmp[i] + offs[i>>10].
// ---------------------------------------------------------------------------
__global__ __launch_bounds__(1024) void scanA(
    const int* __restrict__ G, int* __restrict__ tmp, int* __restrict__ parts, int n)
{
    __shared__ int buf[2][1024];
    const int tid = threadIdx.x;
    int i = blockIdx.x * 1024 + tid;
    int v = (i < n) ? G[i] : 0;
    buf[0][tid] = v;
    __syncthreads();
    int pi = 0;
    for (int off = 1; off < 1024; off <<= 1) {
        int t = buf[pi][tid] + ((tid >= off) ? buf[pi][tid - off] : 0);
        buf[1 - pi][tid] = t;
        pi = 1 - pi;
        __syncthreads();
    }
    if (i < n) tmp[i] = buf[pi][tid] - v;
    if (tid == 1023) parts[blockIdx.x] = buf[pi][1023];
}

__global__ __launch_bounds__(1024) void scanB(
    const int* __restrict__ parts, int* __restrict__ offs,
    int* __restrict__ tot, int np)
{
    __shared__ int buf[2][1024];
    const int t = threadIdx.x;
    int v = (t < np) ? parts[t] : 0;
    buf[0][t] = v;
    __syncthreads();
    int pi = 0;
    for (int off = 1; off < 1024; off <<= 1) {
        int s = buf[pi][t] + ((t >= off) ? buf[pi][t - off] : 0);
        buf[1 - pi][t] = s;
        pi = 1 - pi;
        __syncthreads();
    }
    if (t < np) offs[t] = buf[pi][t] - v;
    if (t == 0) tot[0] = buf[pi][1023];          // n_edges + n_compact
}

// ---------------------------------------------------------------------------
// edge_bin: CSR-place each edge; pack hidx|c; build csrc (redundant stores ok)
// ---------------------------------------------------------------------------
__global__ __launch_bounds__(256) void edge_bin(
    const int* __restrict__ edge_index, const int* __restrict__ edge_type,
    const int* __restrict__ tmp, const int* __restrict__ offs,
    const int* __restrict__ c, int* __restrict__ cnt2,
    unsigned* __restrict__ pk2, int* __restrict__ csrc,
    int n_edges, int n_nodes, int n_rel)
{
    int e = blockIdx.x * 256 + threadIdx.x;
    if (e >= n_edges) return;
    int src = edge_index[e];
    int dst = edge_index[n_edges + e];
    int r   = edge_type[e];
    int pos = tmp[dst] + offs[dst >> 10] + atomicAdd(&cnt2[dst], 1);
    int gi  = n_nodes + r * n_nodes + src;
    int cidx = tmp[gi] + offs[gi >> 10] - n_edges;    // compact rel-row index
    int hidx = n_nodes + cidx;                        // < 2^20
    unsigned cc = (unsigned)c[dst * n_rel + r];
    if (cc > 255u) cc = 255u;
    pk2[pos] = (unsigned)hidx | (cc << 20);
    csrc[cidx] = src;                                 // same-value race: benign
}

// ---------------------------------------------------------------------------
// Phase 1 v5: flat-balanced H GEMM. grid (1024, 1). Flat tile space over all
// segments; equal contiguous chunk per block (chunk computed in-kernel from
// device-side compaction counts). B-frags register-resident, reloaded only at
// segment boundaries. Distance-1 A-frag prefetch.
// ---------------------------------------------------------------------------
__global__ __launch_bounds__(256, 2) void gemm_h(
    const unsigned* __restrict__ XB, const unsigned short* __restrict__ WT,
    const float* __restrict__ bias, const int* __restrict__ csrc,
    const int* __restrict__ tmp, const int* __restrict__ offs,
    const int* __restrict__ tot, unsigned short* __restrict__ H,
    int n_nodes, int n_edges, int n_rel)
{
    __shared__ unsigned short Ht[2][64][D];
    __shared__ int s_end[9];     // cumulative flat-tile end per seg
    __shared__ int s_cnt[9];     // row count per seg
    __shared__ int s_S0[9];      // csrc base per seg
    __shared__ int s_base[9];    // H base row per seg

    const int tid  = threadIdx.x;
    const int wave = tid >> 6;
    const int lane = tid & 63;
    const int l16  = lane & 15;
    const int quad = lane >> 4;
    const int row_off = wave * 16 + l16;
    const int cq8  = quad * 8;

    if (tid == 0) {
        int acc = 0;
        for (int s = 0; s <= n_rel; ++s) {
            int cnt, S0 = 0, base;
            if (s == 0) { cnt = n_nodes; base = 0; }
            else {
                int r = s - 1;
                int gi0 = n_nodes + r * n_nodes;
                S0 = tmp[gi0] + offs[gi0 >> 10] - n_edges;
                int S1 = (r == n_rel - 1)
                         ? (tot[0] - n_edges)
                         : (tmp[gi0 + n_nodes] + offs[(gi0 + n_nodes) >> 10] - n_edges);
                cnt = S1 - S0;
                base = n_nodes + S0;
            }
            acc += (cnt + 63) >> 6;
            s_end[s] = acc; s_cnt[s] = cnt; s_S0[s] = S0; s_base[s] = base;
        }
    }
    __syncthreads();

    const int nflat = s_end[n_rel];
    const int chunk = (nflat + gridDim.x - 1) / gridDim.x;
    const int ft0 = blockIdx.x * chunk;
    int ft1 = ft0 + chunk; if (ft1 > nflat) ft1 = nflat;
    if (ft0 >= ft1) return;

    auto resolve = [&](int ft, int& seg, int& lt) {
        int s = 0;
        while (ft >= s_end[s]) ++s;
        seg = s;
        lt = ft - (s ? s_end[s - 1] : 0);
    };
    auto load_node = [&](int seg, int lt) -> int {
        int lr = lt * 64 + row_off;
        if (lr >= s_cnt[seg]) return 0;
        return (seg == 0) ? lr : csrc[s_S0[seg] + lr];
    };
    auto load_af = [&](int seg, int lt, int node, bf16x8* fr) {
        int lr = lt * 64 + row_off;
        bool v = (lr < s_cnt[seg]);
        const unsigned short* xr = (const unsigned short*)XB + (size_t)node * D + cq8;
#pragma unroll
        for (int kc = 0; kc < 4; ++kc)
            fr[kc] = v ? *(const bf16x8*)(xr + kc * 32)
                       : (bf16x8){0, 0, 0, 0, 0, 0, 0, 0};
    };

    bf16x8 bfr[8][4];
    float bv[8];
    int cur_seg = -1;

    int segA, ltA;
    resolve(ft0, segA, ltA);
    int nodeA = load_node(segA, ltA);
    bf16x8 af[4];
    load_af(segA, ltA, nodeA, af);

    int it = 0;
    for (int ft = ft0; ft < ft1; ++ft, ++it) {
        const int seg = segA, lt = ltA;

        // prefetch next flat tile's A-frags (independent of B/seg state)
        const bool haveN = (ft + 1 < ft1);
        bf16x8 afn[4];
        int segN = 0, ltN = 0;
        if (haveN) {
            resolve(ft + 1, segN, ltN);
            int nodeN = load_node(segN, ltN);
            load_af(segN, ltN, nodeN, afn);
        }

        // (re)load B-frags + bias at segment boundary (<=2 per block)
        if (seg != cur_seg) {
            const unsigned short* Wseg = WT + (size_t)seg * D * D;
#pragma unroll
            for (int nt = 0; nt < 8; ++nt) {
                const unsigned short* bp = Wseg + (size_t)(nt * 16 + l16) * D + cq8;
#pragma unroll
                for (int kc = 0; kc < 4; ++kc)
                    bfr[nt][kc] = *(const bf16x8*)(bp + kc * 32);
                bv[nt] = (seg == 0) ? bias[nt * 16 + l16] : 0.f;
            }
            cur_seg = seg;
        }

        f32x4 acc[8];
#pragma unroll
        for (int nt = 0; nt < 8; ++nt) {
            acc[nt] = (f32x4){0.f, 0.f, 0.f, 0.f};
#pragma unroll
            for (int kc = 0; kc < 4; ++kc)
                acc[nt] = __builtin_amdgcn_mfma_f32_16x16x32_bf16(
                    af[kc], bfr[nt][kc], acc[nt], 0, 0, 0);
        }

        // repack C/D -> row-major bf16 tile (double-buffered) + store
        unsigned short (*Hb)[D] = Ht[it & 1];
#pragma unroll
        for (int nt = 0; nt < 8; ++nt) {
            int col = nt * 16 + l16;
#pragma unroll
            for (int reg = 0; reg < 4; ++reg)
                Hb[wave * 16 + quad * 4 + reg][col] = f32_to_bf16(acc[nt][reg] + bv[nt]);
        }
        lds_barrier();   // ds-order only; global stores/loads stay in flight

        int rows = s_cnt[seg] - lt * 64; if (rows > 64) rows = 64;
        int nu4 = rows * (D / 8);
        const u32x4* srcp = (const u32x4*)&Hb[0][0];
        u32x4* dstp = (u32x4*)(H + ((size_t)(s_base[seg] + lt * 64)) * D);
        for (int i = tid; i < nu4; i += 256) dstp[i] = srcp[i];

        if (haveN) {
            segA = segN; ltA = ltN;
#pragma unroll
            for (int kc = 0; kc < 4; ++kc) af[kc] = afn[kc];
        }
    }
}

// ---------------------------------------------------------------------------
// Phase 2: one wave per dst node; dst made explicitly wave-uniform so
// pk2/bounds go through scalar loads; per-lane work = H load + 2 unpack +
// 2 FMA per edge. 1/c via v_rcp (c is a small integer: error ~1 ulp).
// ---------------------------------------------------------------------------
__global__ __launch_bounds__(256) void gather_out(
    const unsigned short* __restrict__ H, const unsigned* __restrict__ pk2,
    const int* __restrict__ tmp, const int* __restrict__ offs,
    float* __restrict__ out, int n_nodes)
{
    int dst = (blockIdx.x * 256 + threadIdx.x) >> 6;
    const int lane = threadIdx.x & 63;
    if (dst >= n_nodes) return;
    dst = __builtin_amdgcn_readfirstlane(dst);   // wave-uniform by construction

    const unsigned* HH = (const unsigned*)H;
    unsigned u0 = HH[(size_t)dst * 64 + lane];   // root+bias row
    float a0 = bf_lo(u0), a1 = bf_hi(u0);

    const int e0 = tmp[dst] + offs[dst >> 10];
    const int e1 = tmp[dst + 1] + offs[(dst + 1) >> 10];

    for (int base = e0; base < e1; base += 8) {
        float al[8];
        const unsigned* hp[8];
#pragma unroll
        for (int j = 0; j < 8; ++j) {
            int e = base + j;
            bool ok = (e < e1);
            unsigned p = ok ? pk2[e] : 0u;       // uniform address -> s_load
            al[j] = ok ? __builtin_amdgcn_rcpf((float)(p >> 20)) : 0.f;
            hp[j] = HH + (size_t)(p & 0xFFFFFu) * 64;
        }
        unsigned hv[8];
#pragma unroll
        for (int j = 0; j < 8; ++j) hv[j] = hp[j][lane];
#pragma unroll
        for (int j = 0; j < 8; ++j) {
            a0 += al[j] * bf_lo(hv[j]);
            a1 += al[j] * bf_hi(hv[j]);
        }
    }

    a0 = fmaxf(a0, 0.f); a1 = fmaxf(a1, 0.f);
    *(float2*)(out + (size_t)dst * D + 2 * lane) = make_float2(a0, a1);
}

extern "C" void kernel_launch(void* const* d_in, const int* in_sizes, int n_in,
                              void* d_out, int out_size, void* d_ws, size_t ws_size,
                              hipStream_t stream) {
    const float* x          = (const float*)d_in[0];
    const int*   edge_index = (const int*)d_in[1];
    const int*   edge_type  = (const int*)d_in[2];
    const float* W          = (const float*)d_in[3];
    const float* root       = (const float*)d_in[4];
    const float* bias       = (const float*)d_in[5];
    float* out = (float*)d_out;

    const int n_nodes = in_sizes[0] / D;          // 100000
    const int n_edges = in_sizes[2];              // 600000
    const int n_rel   = in_sizes[3] / (D * D);    // 8
    const int nsegs   = n_rel + 1;
    const int nG      = n_nodes * nsegs;          // 900000

    // ws layout (worst-case compact rows = n_nodes + n_edges)
    char* p = (char*)d_ws;
    auto alloc = [&](size_t bytes) {
        char* q = p; p += (bytes + 255) & ~(size_t)255; return q;
    };
    int* c      = (int*)alloc((size_t)n_nodes * n_rel * 4);
    int* G      = (int*)alloc((size_t)(nG + 1) * 4);
    int* tmp    = (int*)alloc((size_t)(nG + 1) * 4);
    int* parts  = (int*)alloc(4096);
    int* offs   = (int*)alloc(4096);
    int* tot    = (int*)alloc(256);
    int* cnt2   = (int*)alloc((size_t)n_nodes * 4);
    unsigned* pk2 = (unsigned*)alloc((size_t)n_edges * 4);
    unsigned* XB  = (unsigned*)alloc((size_t)n_nodes * (D / 2) * 4);
    unsigned short* WT = (unsigned short*)alloc((size_t)nsegs * D * D * 2);
    int* csrc   = (int*)alloc((size_t)n_edges * 4);
    unsigned short* H = (unsigned short*)p;       // worst (n_nodes+n_edges) rows

    const int nquads   = n_nodes * (D / 4);
    const int wt_total = nsegs * D * D;
    int prep_n = nquads;
    if (wt_total > prep_n) prep_n = wt_total;
    if (nG > prep_n) prep_n = nG;

    const int egrid = (n_edges + 255) / 256;
    const int nA = (nG + 1023) / 1024;            // 879 <= 1024

    prep_all<<<(prep_n + 255) / 256, 256, 0, stream>>>(
        x, W, root, XB, WT, c, G, cnt2, nquads, wt_total, n_nodes, n_rel);
    edge_hist<<<egrid, 256, 0, stream>>>(
        edge_index, edge_type, c, G, n_edges, n_nodes, n_rel);
    scanA<<<nA, 1024, 0, stream>>>(G, tmp, parts, nG);
    scanB<<<1, 1024, 0, stream>>>(parts, offs, tot, nA);
    edge_bin<<<egrid, 256, 0, stream>>>(
        edge_index, edge_type, tmp, offs, c, cnt2, pk2, csrc,
        n_edges, n_nodes, n_rel);
    gemm_h<<<1024, 256, 0, stream>>>(
        XB, WT, bias, csrc, tmp, offs, tot, H, n_nodes, n_edges, n_rel);
    gather_out<<<(n_nodes + 3) / 4, 256, 0, stream>>>(
        H, pk2, tmp, offs, out, n_nodes);
}